// Round 4
// baseline (143.272 us; speedup 1.0000x reference)
//
#include <hip/hip_runtime.h>
#include <hip/hip_bf16.h>
#include <hip/hip_fp16.h>

#define Hh 160
#define Ww 160
#define Cc 64
#define HWc 25600
#define Bb 4
#define AST 76  // A-tile row stride in halves (152B): conflict-light b128 reads

typedef __attribute__((ext_vector_type(8))) _Float16 half8;
typedef __attribute__((ext_vector_type(4))) float f32x4;

__device__ __forceinline__ unsigned int f2h2u(float a, float b) {
  __half2 h = __floats2half2_rn(a, b);
  return *(unsigned int*)&h;
}

// ---------------------------------------------------------------------------
// Kernel P: role-split prep (unchanged).
// ---------------------------------------------------------------------------
__global__ __launch_bounds__(256) void k_prep(
    const float* __restrict__ x, const float* __restrict__ wm,
    const float* __restrict__ wn, const float* __restrict__ ow,
    unsigned short* __restrict__ xT, unsigned short* __restrict__ bf) {
  if (blockIdx.x < 400) {
    __shared__ unsigned short s[64][260];
    int wg = blockIdx.x;  // 400 = 4b * 100
    int b = wg / 100;
    int pix0 = (wg % 100) * 256;
    int l = threadIdx.x & 63, wv = threadIdx.x >> 6;
    const float* xb = x + (size_t)b * Cc * HWc + pix0;
#pragma unroll
    for (int i = 0; i < 16; i++) {
      int c = i * 4 + wv;
      float4 v = *(const float4*)&xb[(size_t)c * HWc + l * 4];
      *(uint2*)&s[c][l * 4] = make_uint2(f2h2u(v.x, v.y), f2h2u(v.z, v.w));
    }
    __syncthreads();
    int p = threadIdx.x;  // pixel 0..255
    unsigned int w[32];
#pragma unroll
    for (int j = 0; j < 32; j++) {
      unsigned int a = s[2 * j][p];
      unsigned int bb = s[2 * j + 1][p];
      w[j] = (a & 0xffffu) | (bb << 16);
    }
    unsigned short* dst = xT + ((size_t)(b * HWc + pix0 + p)) * 64;
#pragma unroll
    for (int j = 0; j < 8; j++)
      ((uint4*)dst)[j] = make_uint4(w[4 * j], w[4 * j + 1], w[4 * j + 2], w[4 * j + 3]);
  } else {
    int i = (blockIdx.x - 400) * 256 + threadIdx.x;
    if (i < 9 * 2 * 12 * 64 * 8) {
      int j2 = i & 7;
      int lane = (i >> 3) & 63;
      int ntck = i >> 9;
      int nt = ntck % 12;
      int ck = ntck / 12;
      int kk = ck >> 1;
      int chunk = ck & 1;
      int n = nt * 16 + (lane & 15);
      int c = chunk * 32 + (lane >> 4) * 8 + j2;
      float v;
      if (n < 64)
        v = wm[(n * 64 + c) * 9 + kk] + wm[((n + 64) * 64 + c) * 9 + kk];
      else
        v = wn[((n - 64) * 64 + c) * 9 + kk];
      __half hv = __float2half_rn(v);
      bf[i] = *(unsigned short*)&hv;
    } else if (i < 9 * 2 * 12 * 64 * 8 + 2 * 2 * 64 * 8) {
      int j = i - 9 * 2 * 12 * 64 * 8;
      int j2 = j & 7;
      int lane = (j >> 3) & 63;
      int rest = j >> 9;  // chunk*2 + ntile
      int ntile = rest & 1;
      int chunk = rest >> 1;
      int n = ntile * 16 + (lane & 15);
      int c = chunk * 32 + (lane >> 4) * 8 + j2;
      if (n < 18) {
        __half hv = __float2half_rn(ow[n * 64 + c]);
        bf[i] = *(unsigned short*)&hv;
      } else {
        bf[i] = 0;
      }
    }
  }
}

// ---------------------------------------------------------------------------
// Kernel M. R4: back to 64-px/256-thr/1600-block shape (R3's 128-px tile
// spilled: WRITE 56MB vs 26MB output). Dropped R2's wf register prefetch
// (neutral + spill source). ONE structural change: 2-DEEP gather pipeline.
// A[] is triple-buffered; gathers for kk+2 are issued at phase kk into one
// of two alternating register batches (gA even-kk, gB odd-kk; compile-time
// selection under full unroll), so the combine at phase kk consumes loads
// issued a FULL phase (~800cy) earlier -> L2-miss/L3 gather latency covered.
// Barriers stay lgkm-only: register-destined loads legally cross them.
// ---------------------------------------------------------------------------
__device__ __forceinline__ void gather_issue(const char* __restrict__ gbase,
                                             uint4 D, int chB, uint4& c00,
                                             uint4& c01, uint4& c10,
                                             uint4& c11) {
  int bb = (int)D.x + chB;
  int dxB = (int)(D.y & 0xffffu);
  int dyB = (int)(D.y >> 16);
  c00 = *(const uint4*)(gbase + bb);
  c01 = *(const uint4*)(gbase + bb + dxB);
  c10 = *(const uint4*)(gbase + bb + dyB);
  c11 = *(const uint4*)(gbase + bb + dxB + dyB);
}

__device__ __forceinline__ void combine_write(unsigned short* Arow, uint2 Wzw,
                                              const uint4& c00, const uint4& c01,
                                              const uint4& c10,
                                              const uint4& c11) {
  __half2 wz = *(const __half2*)&Wzw.x;
  __half2 ww = *(const __half2*)&Wzw.y;
  __half2 W00 = __half2half2(__low2half(wz));
  __half2 W01 = __half2half2(__high2half(wz));
  __half2 W10 = __half2half2(__low2half(ww));
  __half2 W11 = __half2half2(__high2half(ww));
  const unsigned int* a = (const unsigned int*)&c00;
  const unsigned int* b = (const unsigned int*)&c01;
  const unsigned int* c = (const unsigned int*)&c10;
  const unsigned int* d = (const unsigned int*)&c11;
  unsigned int o[4];
#pragma unroll
  for (int j = 0; j < 4; j++) {
    __half2 ha = *(const __half2*)&a[j];
    __half2 hb = *(const __half2*)&b[j];
    __half2 hc = *(const __half2*)&c[j];
    __half2 hd = *(const __half2*)&d[j];
    __half2 r = __hfma2(ha, W00,
                        __hfma2(hb, W01, __hfma2(hc, W10, __hmul2(hd, W11))));
    o[j] = *(unsigned int*)&r;
  }
  *(uint4*)Arow = make_uint4(o[0], o[1], o[2], o[3]);
}

__global__ __launch_bounds__(256, 4) void k_main(
    const unsigned short* __restrict__ xT, const float* __restrict__ w0,
    const float* __restrict__ off_b, const unsigned short* __restrict__ bfrag,
    const unsigned short* __restrict__ obfrag, float* __restrict__ out) {
  __shared__ unsigned short A[3][64 * AST];  // [buf][px][c], f16 (triple buf)
  __shared__ uint4 gdesc[576];               // per (kk,px) gather descriptor
  float2* spy = (float2*)&A[0][0];           // overlay, dead after desc build
  const uint2* gdw = (const uint2*)gdesc;    // .zw view: index e*2+1
  const int tid = threadIdx.x;
  const int wg = blockIdx.x;  // 1600
  const int band = wg & 7;    // XCD id under round-robin
  const int local = wg >> 3;  // 0..199
  const int b = local / 50;
  const int pix0 = band * 3200 + (local % 50) * 64;
  const int wv = tid >> 6;
  const int l = tid & 63;
  const int lm = l & 15;
  const int quad = l >> 4;
  const int ch8 = l & 7;  // channel octet (16 B)
  const int pr = l >> 3;  // pixel-in-batch 0..7
  const int chB = ch8 * 16;
  const int pl0 = wv * 16 + pr;
  const int pl1 = wv * 16 + 8 + pr;

  const unsigned short* xTb = xT + (size_t)b * HWc * 64;
  const char* gbase = (const char*)xTb;

  f32x4 acc[3][4];
  const f32x4 zero = {0.f, 0.f, 0.f, 0.f};
#pragma unroll
  for (int j = 0; j < 3; j++)
#pragma unroll
    for (int pt = 0; pt < 4; pt++) acc[j][pt] = zero;

  // ---- phase 0: offsets via MFMA -> spy (overlay) ----
  {
    f32x4 aO0 = zero, aO1 = zero;
    const unsigned short* xrow = xTb + (size_t)(pix0 + wv * 16 + lm) * 64;
#pragma unroll
    for (int chunk = 0; chunk < 2; chunk++) {
      half8 sb = *(const half8*)(xrow + chunk * 32 + quad * 8);
      half8 wf0 = *(const half8*)&obfrag[((chunk * 2 + 0) * 64 + l) * 8];
      half8 wf1 = *(const half8*)&obfrag[((chunk * 2 + 1) * 64 + l) * 8];
      aO0 = __builtin_amdgcn_mfma_f32_16x16x32_f16(wf0, sb, aO0, 0, 0, 0);
      aO1 = __builtin_amdgcn_mfma_f32_16x16x32_f16(wf1, sb, aO1, 0, 0, 0);
    }
    int pix = pix0 + wv * 16 + lm;
    int h = pix / Ww, w = pix % Ww;
    float fh = (float)h, fw = (float)w;
#pragma unroll
    for (int rr = 0; rr < 2; rr++) {
      int n = quad * 4 + 2 * rr;
      int kk = n >> 1;
      float oy = aO0[2 * rr] + off_b[n];
      float ox = aO0[2 * rr + 1] + off_b[n + 1];
      oy = fminf(fmaxf(oy, -fh), 160.0f - fh);
      ox = fminf(fmaxf(ox, -fw), 160.0f - fw);
      if (fabsf(oy) >= 8.0f) oy = 8.0f * tanhf(oy * 0.125f);
      if (fabsf(ox) >= 8.0f) ox = 8.0f * tanhf(ox * 0.125f);
      spy[kk * 64 + wv * 16 + lm] =
          make_float2(fh - 1.0f + (float)(kk / 3) + oy,
                      fw - 1.0f + (float)(kk % 3) + ox);
    }
    if (quad == 0) {  // kk=8 from tile1 rows 16,17
      float oy = aO1[0] + off_b[16];
      float ox = aO1[1] + off_b[17];
      oy = fminf(fmaxf(oy, -fh), 160.0f - fh);
      ox = fminf(fmaxf(ox, -fw), 160.0f - fw);
      if (fabsf(oy) >= 8.0f) oy = 8.0f * tanhf(oy * 0.125f);
      if (fabsf(ox) >= 8.0f) ox = 8.0f * tanhf(ox * 0.125f);
      spy[8 * 64 + wv * 16 + lm] =
          make_float2(fh + 1.0f + oy, fw + 1.0f + ox);
    }
  }
  __syncthreads();

  // ---- descriptor build: 576 entries over 256 threads ----
  for (int e = tid; e < 576; e += 256) {
    float2 P = spy[e];
    float py = P.x, pxv = P.y;
    float y0f = floorf(py), x0f = floorf(pxv);
    float wy = py - y0f, wx = pxv - x0f;
    int y0 = (int)y0f, x0 = (int)x0f;
    float vy0 = (y0 >= 0 && y0 < Hh) ? 1.f : 0.f;
    float vy1 = (y0 >= -1 && y0 < Hh - 1) ? 1.f : 0.f;
    float vx0 = (x0 >= 0 && x0 < Ww) ? 1.f : 0.f;
    float vx1 = (x0 >= -1 && x0 < Ww - 1) ? 1.f : 0.f;
    int r0 = min(max(y0, 0), Hh - 1);
    int r1 = min(max(y0 + 1, 0), Hh - 1);
    int c0 = min(max(x0, 0), Ww - 1);
    int c1 = min(max(x0 + 1, 0), Ww - 1);
    float w00 = (1.f - wy) * (1.f - wx) * vy0 * vx0;
    float w01 = (1.f - wy) * wx * vy0 * vx1;
    float w10 = wy * (1.f - wx) * vy1 * vx0;
    float w11 = wy * wx * vy1 * vx1;
    uint4 D;
    D.x = (unsigned int)((r0 * Ww + c0) * 128);
    D.y = (unsigned int)((c1 - c0) * 128) |
          ((unsigned int)((r1 - r0) * Ww * 128) << 16);
    D.z = f2h2u(w00, w01);
    D.w = f2h2u(w10, w11);
    gdesc[e] = D;
  }
  __syncthreads();

  // ---- pipeline prologue: issue kk=0 (gA) and kk=1 (gB); combine kk=0 ----
  uint4 gA[8], gB[8];
  {
    uint4 D0 = gdesc[pl0], D1 = gdesc[pl1];
    gather_issue(gbase, D0, chB, gA[0], gA[1], gA[2], gA[3]);
    gather_issue(gbase, D1, chB, gA[4], gA[5], gA[6], gA[7]);
    uint4 E0 = gdesc[64 + pl0], E1 = gdesc[64 + pl1];
    gather_issue(gbase, E0, chB, gB[0], gB[1], gB[2], gB[3]);
    gather_issue(gbase, E1, chB, gB[4], gB[5], gB[6], gB[7]);
    combine_write(&A[0][pl0 * AST + ch8 * 8], make_uint2(D0.z, D0.w), gA[0],
                  gA[1], gA[2], gA[3]);
    combine_write(&A[0][pl1 * AST + ch8 * 8], make_uint2(D1.z, D1.w), gA[4],
                  gA[5], gA[6], gA[7]);
  }
  asm volatile("s_waitcnt lgkmcnt(0)" ::: "memory");
  __builtin_amdgcn_s_barrier();

#pragma unroll
  for (int kk = 0; kk < 9; kk++) {
    // issue gathers for kk+2 into batch[kk&1] (that batch's data was
    // combined last phase; its regs are free). Compile-time branch.
    if (kk < 7) {
      uint4 D0 = gdesc[(kk + 2) * 64 + pl0];
      uint4 D1 = gdesc[(kk + 2) * 64 + pl1];
      if ((kk & 1) == 0) {
        gather_issue(gbase, D0, chB, gA[0], gA[1], gA[2], gA[3]);
        gather_issue(gbase, D1, chB, gA[4], gA[5], gA[6], gA[7]);
      } else {
        gather_issue(gbase, D0, chB, gB[0], gB[1], gB[2], gB[3]);
        gather_issue(gbase, D1, chB, gB[4], gB[5], gB[6], gB[7]);
      }
    }
    // MFMA on current buffer A[kk%3]; weights loaded inline (R2 showed
    // their latency is hidden by TLP)
#pragma unroll
    for (int chunk = 0; chunk < 2; chunk++) {
      half8 sfr[4];
#pragma unroll
      for (int pt = 0; pt < 4; pt++)
        sfr[pt] = *(const half8*)&A[kk % 3][(pt * 16 + lm) * AST + chunk * 32 +
                                            quad * 8];
      half8 wfr[3];
#pragma unroll
      for (int j = 0; j < 3; j++) {
        int nt = j * 4 + wv;
        wfr[j] = *(const half8*)&bfrag[((size_t)((kk * 2 + chunk) * 12 + nt) *
                                           64 + l) * 8];
      }
#pragma unroll
      for (int j = 0; j < 3; j++)
#pragma unroll
        for (int pt = 0; pt < 4; pt++)
          acc[j][pt] = __builtin_amdgcn_mfma_f32_16x16x32_f16(
              wfr[j], sfr[pt], acc[j][pt], 0, 0, 0);
    }
    // combine kk+1 (issued a FULL phase ago -> latency covered) into
    // A[(kk+1)%3]; weights re-read from gdesc (.zw) to save registers.
    if (kk < 8) {
      uint2 W0 = gdw[((kk + 1) * 64 + pl0) * 2 + 1];
      uint2 W1 = gdw[((kk + 1) * 64 + pl1) * 2 + 1];
      if (((kk + 1) & 1) == 0) {
        combine_write(&A[(kk + 1) % 3][pl0 * AST + ch8 * 8], W0, gA[0], gA[1],
                      gA[2], gA[3]);
        combine_write(&A[(kk + 1) % 3][pl1 * AST + ch8 * 8], W1, gA[4], gA[5],
                      gA[6], gA[7]);
      } else {
        combine_write(&A[(kk + 1) % 3][pl0 * AST + ch8 * 8], W0, gB[0], gB[1],
                      gB[2], gB[3]);
        combine_write(&A[(kk + 1) % 3][pl1 * AST + ch8 * 8], W1, gB[4], gB[5],
                      gB[6], gB[7]);
      }
      asm volatile("s_waitcnt lgkmcnt(0)" ::: "memory");
      __builtin_amdgcn_s_barrier();
    }
  }

  // ---- epilogue: out = (pm + w0) / (1 + |qn0| + |qn1|) ----
  float w0v[4];
#pragma unroll
  for (int r = 0; r < 4; r++) w0v[r] = w0[wv * 16 + quad * 4 + r];
  float* ob = out + (size_t)b * Cc * HWc + pix0;
#pragma unroll
  for (int pt = 0; pt < 4; pt++) {
#pragma unroll
    for (int r = 0; r < 4; r++) {
      int oc = wv * 16 + quad * 4 + r;
      float pm = acc[0][pt][r] + w0v[r];
      float qn = 1.0f + fabsf(acc[1][pt][r]) + fabsf(acc[2][pt][r]);
      ob[oc * HWc + pt * 16 + lm] = pm / qn;
    }
  }
}

extern "C" void kernel_launch(void* const* d_in, const int* in_sizes, int n_in,
                              void* d_out, int out_size, void* d_ws, size_t ws_size,
                              hipStream_t stream) {
  const float* x = (const float*)d_in[0];      // [4,64,160,160]
  const float* off_w = (const float*)d_in[1];  // [18,64]
  const float* off_b = (const float*)d_in[2];  // [18]
  const float* w_m = (const float*)d_in[3];    // [128,64,3,3]
  const float* w_n = (const float*)d_in[4];    // [128,64,3,3]
  const float* w0 = (const float*)d_in[5];     // [64]
  float* out = (float*)d_out;                  // [4,64,160,160]

  // ws layout: bfrag 221184 B | obfrag 4096 B | xT 13107200 B  (~13.3 MB)
  unsigned short* bfrag = (unsigned short*)d_ws;
  unsigned short* obfrag = (unsigned short*)((char*)d_ws + (size_t)221184);
  unsigned short* xT = (unsigned short*)((char*)d_ws + (size_t)225280);

  hipLaunchKernelGGL(k_prep, dim3(840), dim3(256), 0, stream, x, w_m, w_n,
                     off_w, xT, bfrag);
  hipLaunchKernelGGL(k_main, dim3(1600), dim3(256), 0, stream, xT, w0, off_b,
                     bfrag, obfrag, out);
}

// Round 5
// 141.040 us; speedup vs baseline: 1.0158x; 1.0158x over previous
//
#include <hip/hip_runtime.h>
#include <hip/hip_bf16.h>
#include <hip/hip_fp16.h>

#define Hh 160
#define Ww 160
#define Cc 64
#define HWc 25600
#define Bb 4
#define AST 76  // A-tile row stride in halves (152B): conflict-light b128 reads

typedef __attribute__((ext_vector_type(8))) _Float16 half8;
typedef __attribute__((ext_vector_type(4))) float f32x4;

__device__ __forceinline__ unsigned int f2h2u(float a, float b) {
  __half2 h = __floats2half2_rn(a, b);
  return *(unsigned int*)&h;
}

// ---------------------------------------------------------------------------
// Kernel P: role-split prep (unchanged).
// ---------------------------------------------------------------------------
__global__ __launch_bounds__(256) void k_prep(
    const float* __restrict__ x, const float* __restrict__ wm,
    const float* __restrict__ wn, const float* __restrict__ ow,
    unsigned short* __restrict__ xT, unsigned short* __restrict__ bf) {
  if (blockIdx.x < 400) {
    __shared__ unsigned short s[64][260];
    int wg = blockIdx.x;  // 400 = 4b * 100
    int b = wg / 100;
    int pix0 = (wg % 100) * 256;
    int l = threadIdx.x & 63, wv = threadIdx.x >> 6;
    const float* xb = x + (size_t)b * Cc * HWc + pix0;
#pragma unroll
    for (int i = 0; i < 16; i++) {
      int c = i * 4 + wv;
      float4 v = *(const float4*)&xb[(size_t)c * HWc + l * 4];
      *(uint2*)&s[c][l * 4] = make_uint2(f2h2u(v.x, v.y), f2h2u(v.z, v.w));
    }
    __syncthreads();
    int p = threadIdx.x;  // pixel 0..255
    unsigned int w[32];
#pragma unroll
    for (int j = 0; j < 32; j++) {
      unsigned int a = s[2 * j][p];
      unsigned int bb = s[2 * j + 1][p];
      w[j] = (a & 0xffffu) | (bb << 16);
    }
    unsigned short* dst = xT + ((size_t)(b * HWc + pix0 + p)) * 64;
#pragma unroll
    for (int j = 0; j < 8; j++)
      ((uint4*)dst)[j] = make_uint4(w[4 * j], w[4 * j + 1], w[4 * j + 2], w[4 * j + 3]);
  } else {
    int i = (blockIdx.x - 400) * 256 + threadIdx.x;
    if (i < 9 * 2 * 12 * 64 * 8) {
      int j2 = i & 7;
      int lane = (i >> 3) & 63;
      int ntck = i >> 9;
      int nt = ntck % 12;
      int ck = ntck / 12;
      int kk = ck >> 1;
      int chunk = ck & 1;
      int n = nt * 16 + (lane & 15);
      int c = chunk * 32 + (lane >> 4) * 8 + j2;
      float v;
      if (n < 64)
        v = wm[(n * 64 + c) * 9 + kk] + wm[((n + 64) * 64 + c) * 9 + kk];
      else
        v = wn[((n - 64) * 64 + c) * 9 + kk];
      __half hv = __float2half_rn(v);
      bf[i] = *(unsigned short*)&hv;
    } else if (i < 9 * 2 * 12 * 64 * 8 + 2 * 2 * 64 * 8) {
      int j = i - 9 * 2 * 12 * 64 * 8;
      int j2 = j & 7;
      int lane = (j >> 3) & 63;
      int rest = j >> 9;  // chunk*2 + ntile
      int ntile = rest & 1;
      int chunk = rest >> 1;
      int n = ntile * 16 + (lane & 15);
      int c = chunk * 32 + (lane >> 4) * 8 + j2;
      if (n < 18) {
        __half hv = __float2half_rn(ow[n * 64 + c]);
        bf[i] = *(unsigned short*)&hv;
      } else {
        bf[i] = 0;
      }
    }
  }
}

// ---------------------------------------------------------------------------
// Kernel M. R5: R0 structure with ONE scheduling change, zero net register
// cost. Diagnosis: vmcnt retires IN ORDER, so R0's phase order (gathers
// issued, then weight loads, then MFMA-waits-weights) forced vmcnt(0) at
// every chunk-0 MFMA -> drained the just-issued gathers -> ~400-500cy
// exposed stall per phase. R2 fixed this but spilled (+48 regs); R4 went
// 2-deep and spilled (+64 regs). R5: SINGLE gather batch, issued one phase
// EARLY: phase kk = MFMA(kk) -> combine(kk+1) [gathered last phase, full
// phase of latency cover; vmcnt wait ~free] -> reissue gathers(kk+2) into
// the same regs -> lgkm-only barrier (loads stay in flight across it;
// pattern correctness-proven in R2/R4). Weight-wait now drains only
// long-landed gathers (free).
// ---------------------------------------------------------------------------
__device__ __forceinline__ void gather_issue(const char* __restrict__ gbase,
                                             uint4 D, int chB, uint4& c00,
                                             uint4& c01, uint4& c10,
                                             uint4& c11) {
  int bb = (int)D.x + chB;
  int dxB = (int)(D.y & 0xffffu);
  int dyB = (int)(D.y >> 16);
  c00 = *(const uint4*)(gbase + bb);
  c01 = *(const uint4*)(gbase + bb + dxB);
  c10 = *(const uint4*)(gbase + bb + dyB);
  c11 = *(const uint4*)(gbase + bb + dxB + dyB);
}

__device__ __forceinline__ void combine_write(unsigned short* Arow, uint2 Wzw,
                                              const uint4& c00, const uint4& c01,
                                              const uint4& c10,
                                              const uint4& c11) {
  __half2 wz = *(const __half2*)&Wzw.x;
  __half2 ww = *(const __half2*)&Wzw.y;
  __half2 W00 = __half2half2(__low2half(wz));
  __half2 W01 = __half2half2(__high2half(wz));
  __half2 W10 = __half2half2(__low2half(ww));
  __half2 W11 = __half2half2(__high2half(ww));
  const unsigned int* a = (const unsigned int*)&c00;
  const unsigned int* b = (const unsigned int*)&c01;
  const unsigned int* c = (const unsigned int*)&c10;
  const unsigned int* d = (const unsigned int*)&c11;
  unsigned int o[4];
#pragma unroll
  for (int j = 0; j < 4; j++) {
    __half2 ha = *(const __half2*)&a[j];
    __half2 hb = *(const __half2*)&b[j];
    __half2 hc = *(const __half2*)&c[j];
    __half2 hd = *(const __half2*)&d[j];
    __half2 r = __hfma2(ha, W00,
                        __hfma2(hb, W01, __hfma2(hc, W10, __hmul2(hd, W11))));
    o[j] = *(unsigned int*)&r;
  }
  *(uint4*)Arow = make_uint4(o[0], o[1], o[2], o[3]);
}

__global__ __launch_bounds__(256, 4) void k_main(
    const unsigned short* __restrict__ xT, const float* __restrict__ w0,
    const float* __restrict__ off_b, const unsigned short* __restrict__ bfrag,
    const unsigned short* __restrict__ obfrag, float* __restrict__ out) {
  __shared__ unsigned short A[2][64 * AST];  // [buf][px][c], f16
  __shared__ uint4 gdesc[576];               // per (kk,px) gather descriptor
  float2* spy = (float2*)&A[0][0];           // overlay, dead after desc build
  const uint2* gdw = (const uint2*)gdesc;    // .zw view: index e*2+1
  const int tid = threadIdx.x;
  const int wg = blockIdx.x;  // 1600
  const int band = wg & 7;    // XCD id under round-robin
  const int local = wg >> 3;  // 0..199
  const int b = local / 50;
  const int pix0 = band * 3200 + (local % 50) * 64;
  const int wv = tid >> 6;
  const int l = tid & 63;
  const int lm = l & 15;
  const int quad = l >> 4;
  const int ch8 = l & 7;  // channel octet (16 B)
  const int pr = l >> 3;  // pixel-in-batch 0..7
  const int chB = ch8 * 16;
  const int pl0 = wv * 16 + pr;
  const int pl1 = wv * 16 + 8 + pr;

  const unsigned short* xTb = xT + (size_t)b * HWc * 64;
  const char* gbase = (const char*)xTb;

  f32x4 acc[3][4];
  const f32x4 zero = {0.f, 0.f, 0.f, 0.f};
#pragma unroll
  for (int j = 0; j < 3; j++)
#pragma unroll
    for (int pt = 0; pt < 4; pt++) acc[j][pt] = zero;

  // ---- phase 0: offsets via MFMA -> spy (overlay) ----
  {
    f32x4 aO0 = zero, aO1 = zero;
    const unsigned short* xrow = xTb + (size_t)(pix0 + wv * 16 + lm) * 64;
#pragma unroll
    for (int chunk = 0; chunk < 2; chunk++) {
      half8 sb = *(const half8*)(xrow + chunk * 32 + quad * 8);
      half8 wf0 = *(const half8*)&obfrag[((chunk * 2 + 0) * 64 + l) * 8];
      half8 wf1 = *(const half8*)&obfrag[((chunk * 2 + 1) * 64 + l) * 8];
      aO0 = __builtin_amdgcn_mfma_f32_16x16x32_f16(wf0, sb, aO0, 0, 0, 0);
      aO1 = __builtin_amdgcn_mfma_f32_16x16x32_f16(wf1, sb, aO1, 0, 0, 0);
    }
    int pix = pix0 + wv * 16 + lm;
    int h = pix / Ww, w = pix % Ww;
    float fh = (float)h, fw = (float)w;
#pragma unroll
    for (int rr = 0; rr < 2; rr++) {
      int n = quad * 4 + 2 * rr;
      int kk = n >> 1;
      float oy = aO0[2 * rr] + off_b[n];
      float ox = aO0[2 * rr + 1] + off_b[n + 1];
      oy = fminf(fmaxf(oy, -fh), 160.0f - fh);
      ox = fminf(fmaxf(ox, -fw), 160.0f - fw);
      if (fabsf(oy) >= 8.0f) oy = 8.0f * tanhf(oy * 0.125f);
      if (fabsf(ox) >= 8.0f) ox = 8.0f * tanhf(ox * 0.125f);
      spy[kk * 64 + wv * 16 + lm] =
          make_float2(fh - 1.0f + (float)(kk / 3) + oy,
                      fw - 1.0f + (float)(kk % 3) + ox);
    }
    if (quad == 0) {  // kk=8 from tile1 rows 16,17
      float oy = aO1[0] + off_b[16];
      float ox = aO1[1] + off_b[17];
      oy = fminf(fmaxf(oy, -fh), 160.0f - fh);
      ox = fminf(fmaxf(ox, -fw), 160.0f - fw);
      if (fabsf(oy) >= 8.0f) oy = 8.0f * tanhf(oy * 0.125f);
      if (fabsf(ox) >= 8.0f) ox = 8.0f * tanhf(ox * 0.125f);
      spy[8 * 64 + wv * 16 + lm] =
          make_float2(fh + 1.0f + oy, fw + 1.0f + ox);
    }
  }
  __syncthreads();

  // ---- descriptor build: 576 entries over 256 threads ----
  for (int e = tid; e < 576; e += 256) {
    float2 P = spy[e];
    float py = P.x, pxv = P.y;
    float y0f = floorf(py), x0f = floorf(pxv);
    float wy = py - y0f, wx = pxv - x0f;
    int y0 = (int)y0f, x0 = (int)x0f;
    float vy0 = (y0 >= 0 && y0 < Hh) ? 1.f : 0.f;
    float vy1 = (y0 >= -1 && y0 < Hh - 1) ? 1.f : 0.f;
    float vx0 = (x0 >= 0 && x0 < Ww) ? 1.f : 0.f;
    float vx1 = (x0 >= -1 && x0 < Ww - 1) ? 1.f : 0.f;
    int r0 = min(max(y0, 0), Hh - 1);
    int r1 = min(max(y0 + 1, 0), Hh - 1);
    int c0 = min(max(x0, 0), Ww - 1);
    int c1 = min(max(x0 + 1, 0), Ww - 1);
    float w00 = (1.f - wy) * (1.f - wx) * vy0 * vx0;
    float w01 = (1.f - wy) * wx * vy0 * vx1;
    float w10 = wy * (1.f - wx) * vy1 * vx0;
    float w11 = wy * wx * vy1 * vx1;
    uint4 D;
    D.x = (unsigned int)((r0 * Ww + c0) * 128);
    D.y = (unsigned int)((c1 - c0) * 128) |
          ((unsigned int)((r1 - r0) * Ww * 128) << 16);
    D.z = f2h2u(w00, w01);
    D.w = f2h2u(w10, w11);
    gdesc[e] = D;
  }
  __syncthreads();

  // ---- prologue: gather+combine kk=0 into buf 0; issue gathers kk=1 ----
  uint4 g[8];  // single gather batch, static indices only
  {
    uint4 D0 = gdesc[pl0], D1 = gdesc[pl1];
    gather_issue(gbase, D0, chB, g[0], g[1], g[2], g[3]);
    gather_issue(gbase, D1, chB, g[4], g[5], g[6], g[7]);
    combine_write(&A[0][pl0 * AST + ch8 * 8], make_uint2(D0.z, D0.w), g[0],
                  g[1], g[2], g[3]);
    combine_write(&A[0][pl1 * AST + ch8 * 8], make_uint2(D1.z, D1.w), g[4],
                  g[5], g[6], g[7]);
    uint4 E0 = gdesc[64 + pl0], E1 = gdesc[64 + pl1];
    gather_issue(gbase, E0, chB, g[0], g[1], g[2], g[3]);
    gather_issue(gbase, E1, chB, g[4], g[5], g[6], g[7]);
  }
  asm volatile("s_waitcnt lgkmcnt(0)" ::: "memory");
  __builtin_amdgcn_s_barrier();

#pragma unroll
  for (int kk = 0; kk < 9; kk++) {
    const int cur = kk & 1;
    // MFMA on current buffer (R0 per-chunk weight loads). The weight-wait's
    // vmcnt(0) drains only LAST-phase gathers, which landed long ago.
#pragma unroll
    for (int chunk = 0; chunk < 2; chunk++) {
      half8 sfr[4];
#pragma unroll
      for (int pt = 0; pt < 4; pt++)
        sfr[pt] = *(const half8*)&A[cur][(pt * 16 + lm) * AST + chunk * 32 +
                                         quad * 8];
      half8 wfr[3];
#pragma unroll
      for (int j = 0; j < 3; j++) {
        int nt = j * 4 + wv;
        wfr[j] = *(const half8*)&bfrag[((size_t)((kk * 2 + chunk) * 12 + nt) *
                                           64 + l) * 8];
      }
#pragma unroll
      for (int j = 0; j < 3; j++)
#pragma unroll
        for (int pt = 0; pt < 4; pt++)
          acc[j][pt] = __builtin_amdgcn_mfma_f32_16x16x32_f16(
              wfr[j], sfr[pt], acc[j][pt], 0, 0, 0);
    }
    // combine kk+1 (gathered one full phase ago -> latency covered) into
    // A[cur^1]; bilinear weights re-read from gdesc (.zw view).
    if (kk < 8) {
      uint2 W0 = gdw[((kk + 1) * 64 + pl0) * 2 + 1];
      uint2 W1 = gdw[((kk + 1) * 64 + pl1) * 2 + 1];
      combine_write(&A[cur ^ 1][pl0 * AST + ch8 * 8], W0, g[0], g[1], g[2],
                    g[3]);
      combine_write(&A[cur ^ 1][pl1 * AST + ch8 * 8], W1, g[4], g[5], g[6],
                    g[7]);
    }
    // reissue gathers for kk+2 into the same regs (dead after combine);
    // they stay in flight across the lgkm-only barrier into next phase.
    if (kk < 7) {
      uint4 D0 = gdesc[(kk + 2) * 64 + pl0];
      uint4 D1 = gdesc[(kk + 2) * 64 + pl1];
      gather_issue(gbase, D0, chB, g[0], g[1], g[2], g[3]);
      gather_issue(gbase, D1, chB, g[4], g[5], g[6], g[7]);
    }
    if (kk < 8) {
      asm volatile("s_waitcnt lgkmcnt(0)" ::: "memory");
      __builtin_amdgcn_s_barrier();
    }
  }

  // ---- epilogue: out = (pm + w0) / (1 + |qn0| + |qn1|) ----
  float w0v[4];
#pragma unroll
  for (int r = 0; r < 4; r++) w0v[r] = w0[wv * 16 + quad * 4 + r];
  float* ob = out + (size_t)b * Cc * HWc + pix0;
#pragma unroll
  for (int pt = 0; pt < 4; pt++) {
#pragma unroll
    for (int r = 0; r < 4; r++) {
      int oc = wv * 16 + quad * 4 + r;
      float pm = acc[0][pt][r] + w0v[r];
      float qn = 1.0f + fabsf(acc[1][pt][r]) + fabsf(acc[2][pt][r]);
      ob[oc * HWc + pt * 16 + lm] = pm / qn;
    }
  }
}

extern "C" void kernel_launch(void* const* d_in, const int* in_sizes, int n_in,
                              void* d_out, int out_size, void* d_ws, size_t ws_size,
                              hipStream_t stream) {
  const float* x = (const float*)d_in[0];      // [4,64,160,160]
  const float* off_w = (const float*)d_in[1];  // [18,64]
  const float* off_b = (const float*)d_in[2];  // [18]
  const float* w_m = (const float*)d_in[3];    // [128,64,3,3]
  const float* w_n = (const float*)d_in[4];    // [128,64,3,3]
  const float* w0 = (const float*)d_in[5];     // [64]
  float* out = (float*)d_out;                  // [4,64,160,160]

  // ws layout: bfrag 221184 B | obfrag 4096 B | xT 13107200 B  (~13.3 MB)
  unsigned short* bfrag = (unsigned short*)d_ws;
  unsigned short* obfrag = (unsigned short*)((char*)d_ws + (size_t)221184);
  unsigned short* xT = (unsigned short*)((char*)d_ws + (size_t)225280);

  hipLaunchKernelGGL(k_prep, dim3(840), dim3(256), 0, stream, x, w_m, w_n,
                     off_w, xT, bfrag);
  hipLaunchKernelGGL(k_main, dim3(1600), dim3(256), 0, stream, xT, w0, off_b,
                     bfrag, obfrag, out);
}

// Round 6
// 131.327 us; speedup vs baseline: 1.0910x; 1.0740x over previous
//
#include <hip/hip_runtime.h>
#include <hip/hip_bf16.h>
#include <hip/hip_fp16.h>

#define Hh 160
#define Ww 160
#define Cc 64
#define HWc 25600
#define Bb 4
#define AST 76  // A-tile row stride in halves (152B): conflict-light b128 reads

typedef __attribute__((ext_vector_type(8))) _Float16 half8;
typedef __attribute__((ext_vector_type(4))) float f32x4;

__device__ __forceinline__ unsigned int f2h2u(float a, float b) {
  __half2 h = __floats2half2_rn(a, b);
  return *(unsigned int*)&h;
}

// ---------------------------------------------------------------------------
// Kernel P: role-split prep (unchanged).
// ---------------------------------------------------------------------------
__global__ __launch_bounds__(256) void k_prep(
    const float* __restrict__ x, const float* __restrict__ wm,
    const float* __restrict__ wn, const float* __restrict__ ow,
    unsigned short* __restrict__ xT, unsigned short* __restrict__ bf) {
  if (blockIdx.x < 400) {
    __shared__ unsigned short s[64][260];
    int wg = blockIdx.x;  // 400 = 4b * 100
    int b = wg / 100;
    int pix0 = (wg % 100) * 256;
    int l = threadIdx.x & 63, wv = threadIdx.x >> 6;
    const float* xb = x + (size_t)b * Cc * HWc + pix0;
#pragma unroll
    for (int i = 0; i < 16; i++) {
      int c = i * 4 + wv;
      float4 v = *(const float4*)&xb[(size_t)c * HWc + l * 4];
      *(uint2*)&s[c][l * 4] = make_uint2(f2h2u(v.x, v.y), f2h2u(v.z, v.w));
    }
    __syncthreads();
    int p = threadIdx.x;  // pixel 0..255
    unsigned int w[32];
#pragma unroll
    for (int j = 0; j < 32; j++) {
      unsigned int a = s[2 * j][p];
      unsigned int bb = s[2 * j + 1][p];
      w[j] = (a & 0xffffu) | (bb << 16);
    }
    unsigned short* dst = xT + ((size_t)(b * HWc + pix0 + p)) * 64;
#pragma unroll
    for (int j = 0; j < 8; j++)
      ((uint4*)dst)[j] = make_uint4(w[4 * j], w[4 * j + 1], w[4 * j + 2], w[4 * j + 3]);
  } else {
    int i = (blockIdx.x - 400) * 256 + threadIdx.x;
    if (i < 9 * 2 * 12 * 64 * 8) {
      int j2 = i & 7;
      int lane = (i >> 3) & 63;
      int ntck = i >> 9;
      int nt = ntck % 12;
      int ck = ntck / 12;
      int kk = ck >> 1;
      int chunk = ck & 1;
      int n = nt * 16 + (lane & 15);
      int c = chunk * 32 + (lane >> 4) * 8 + j2;
      float v;
      if (n < 64)
        v = wm[(n * 64 + c) * 9 + kk] + wm[((n + 64) * 64 + c) * 9 + kk];
      else
        v = wn[((n - 64) * 64 + c) * 9 + kk];
      __half hv = __float2half_rn(v);
      bf[i] = *(unsigned short*)&hv;
    } else if (i < 9 * 2 * 12 * 64 * 8 + 2 * 2 * 64 * 8) {
      int j = i - 9 * 2 * 12 * 64 * 8;
      int j2 = j & 7;
      int lane = (j >> 3) & 63;
      int rest = j >> 9;  // chunk*2 + ntile
      int ntile = rest & 1;
      int chunk = rest >> 1;
      int n = ntile * 16 + (lane & 15);
      int c = chunk * 32 + (lane >> 4) * 8 + j2;
      if (n < 18) {
        __half hv = __float2half_rn(ow[n * 64 + c]);
        bf[i] = *(unsigned short*)&hv;
      } else {
        bf[i] = 0;
      }
    }
  }
}

// ---------------------------------------------------------------------------
// Kernel M. R6: ILP-over-TLP redesign. Root cause of R1-R5 failures: R0's
// live set is ~126 regs vs the 128 cap of launch_bounds(256,4) -> every
// pipelining attempt spilled to scratch (R2 +5MB, R5 +22MB, R3/R4 +40MB of
// HBM traffic), and R0 itself eats a full gather-latency drain per phase
// (in-order vmcnt FIFO: weight-wait = vmcnt(0) over just-issued gathers).
// Fix: launch_bounds(256,2) -> 256-reg budget, 2 blocks/CU. Steady state is
// wait-free: gathers 2 phases ahead (gA/gB alternating), weights 2 phases
// ahead (wfA/wfB double-set), phase order MFMA(kk) -> combine(kk+1)
// [vmcnt leaves this phase's issues outstanding] -> issue g(kk+2), wf(kk+2)
// -> lgkm-only barrier (register-destined loads stay in flight across it;
// correctness-proven R2/R4/R5). State ~196 regs < 256: spill-free.
// ---------------------------------------------------------------------------
__device__ __forceinline__ void gather_issue(const char* __restrict__ gbase,
                                             uint4 D, int chB, uint4& c00,
                                             uint4& c01, uint4& c10,
                                             uint4& c11) {
  int bb = (int)D.x + chB;
  int dxB = (int)(D.y & 0xffffu);
  int dyB = (int)(D.y >> 16);
  c00 = *(const uint4*)(gbase + bb);
  c01 = *(const uint4*)(gbase + bb + dxB);
  c10 = *(const uint4*)(gbase + bb + dyB);
  c11 = *(const uint4*)(gbase + bb + dxB + dyB);
}

__device__ __forceinline__ void combine_write(unsigned short* Arow, uint2 Wzw,
                                              const uint4& c00, const uint4& c01,
                                              const uint4& c10,
                                              const uint4& c11) {
  __half2 wz = *(const __half2*)&Wzw.x;
  __half2 ww = *(const __half2*)&Wzw.y;
  __half2 W00 = __half2half2(__low2half(wz));
  __half2 W01 = __half2half2(__high2half(wz));
  __half2 W10 = __half2half2(__low2half(ww));
  __half2 W11 = __half2half2(__high2half(ww));
  const unsigned int* a = (const unsigned int*)&c00;
  const unsigned int* b = (const unsigned int*)&c01;
  const unsigned int* c = (const unsigned int*)&c10;
  const unsigned int* d = (const unsigned int*)&c11;
  unsigned int o[4];
#pragma unroll
  for (int j = 0; j < 4; j++) {
    __half2 ha = *(const __half2*)&a[j];
    __half2 hb = *(const __half2*)&b[j];
    __half2 hc = *(const __half2*)&c[j];
    __half2 hd = *(const __half2*)&d[j];
    __half2 r = __hfma2(ha, W00,
                        __hfma2(hb, W01, __hfma2(hc, W10, __hmul2(hd, W11))));
    o[j] = *(unsigned int*)&r;
  }
  *(uint4*)Arow = make_uint4(o[0], o[1], o[2], o[3]);
}

__global__ __launch_bounds__(256, 2) void k_main(
    const unsigned short* __restrict__ xT, const float* __restrict__ w0,
    const float* __restrict__ off_b, const unsigned short* __restrict__ bfrag,
    const unsigned short* __restrict__ obfrag, float* __restrict__ out) {
  __shared__ unsigned short A[2][64 * AST];  // [buf][px][c], f16
  __shared__ uint4 gdesc[576];               // per (kk,px) gather descriptor
  float2* spy = (float2*)&A[0][0];           // overlay, dead after desc build
  const uint2* gdw = (const uint2*)gdesc;    // .zw view: index e*2+1
  const int tid = threadIdx.x;
  const int wg = blockIdx.x;  // 1600
  const int band = wg & 7;    // XCD id under round-robin
  const int local = wg >> 3;  // 0..199
  const int b = local / 50;
  const int pix0 = band * 3200 + (local % 50) * 64;
  const int wv = tid >> 6;
  const int l = tid & 63;
  const int lm = l & 15;
  const int quad = l >> 4;
  const int ch8 = l & 7;  // channel octet (16 B)
  const int pr = l >> 3;  // pixel-in-batch 0..7
  const int chB = ch8 * 16;
  const int pl0 = wv * 16 + pr;
  const int pl1 = wv * 16 + 8 + pr;

  const unsigned short* xTb = xT + (size_t)b * HWc * 64;
  const char* gbase = (const char*)xTb;

  f32x4 acc[3][4];
  const f32x4 zero = {0.f, 0.f, 0.f, 0.f};
#pragma unroll
  for (int j = 0; j < 3; j++)
#pragma unroll
    for (int pt = 0; pt < 4; pt++) acc[j][pt] = zero;

  // ---- phase 0: offsets via MFMA -> spy (overlay) ----
  {
    f32x4 aO0 = zero, aO1 = zero;
    const unsigned short* xrow = xTb + (size_t)(pix0 + wv * 16 + lm) * 64;
#pragma unroll
    for (int chunk = 0; chunk < 2; chunk++) {
      half8 sb = *(const half8*)(xrow + chunk * 32 + quad * 8);
      half8 wf0 = *(const half8*)&obfrag[((chunk * 2 + 0) * 64 + l) * 8];
      half8 wf1 = *(const half8*)&obfrag[((chunk * 2 + 1) * 64 + l) * 8];
      aO0 = __builtin_amdgcn_mfma_f32_16x16x32_f16(wf0, sb, aO0, 0, 0, 0);
      aO1 = __builtin_amdgcn_mfma_f32_16x16x32_f16(wf1, sb, aO1, 0, 0, 0);
    }
    int pix = pix0 + wv * 16 + lm;
    int h = pix / Ww, w = pix % Ww;
    float fh = (float)h, fw = (float)w;
#pragma unroll
    for (int rr = 0; rr < 2; rr++) {
      int n = quad * 4 + 2 * rr;
      int kk = n >> 1;
      float oy = aO0[2 * rr] + off_b[n];
      float ox = aO0[2 * rr + 1] + off_b[n + 1];
      oy = fminf(fmaxf(oy, -fh), 160.0f - fh);
      ox = fminf(fmaxf(ox, -fw), 160.0f - fw);
      if (fabsf(oy) >= 8.0f) oy = 8.0f * tanhf(oy * 0.125f);
      if (fabsf(ox) >= 8.0f) ox = 8.0f * tanhf(ox * 0.125f);
      spy[kk * 64 + wv * 16 + lm] =
          make_float2(fh - 1.0f + (float)(kk / 3) + oy,
                      fw - 1.0f + (float)(kk % 3) + ox);
    }
    if (quad == 0) {  // kk=8 from tile1 rows 16,17
      float oy = aO1[0] + off_b[16];
      float ox = aO1[1] + off_b[17];
      oy = fminf(fmaxf(oy, -fh), 160.0f - fh);
      ox = fminf(fmaxf(ox, -fw), 160.0f - fw);
      if (fabsf(oy) >= 8.0f) oy = 8.0f * tanhf(oy * 0.125f);
      if (fabsf(ox) >= 8.0f) ox = 8.0f * tanhf(ox * 0.125f);
      spy[8 * 64 + wv * 16 + lm] =
          make_float2(fh + 1.0f + oy, fw + 1.0f + ox);
    }
  }
  __syncthreads();

  // ---- descriptor build: 576 entries over 256 threads ----
  for (int e = tid; e < 576; e += 256) {
    float2 P = spy[e];
    float py = P.x, pxv = P.y;
    float y0f = floorf(py), x0f = floorf(pxv);
    float wy = py - y0f, wx = pxv - x0f;
    int y0 = (int)y0f, x0 = (int)x0f;
    float vy0 = (y0 >= 0 && y0 < Hh) ? 1.f : 0.f;
    float vy1 = (y0 >= -1 && y0 < Hh - 1) ? 1.f : 0.f;
    float vx0 = (x0 >= 0 && x0 < Ww) ? 1.f : 0.f;
    float vx1 = (x0 >= -1 && x0 < Ww - 1) ? 1.f : 0.f;
    int r0 = min(max(y0, 0), Hh - 1);
    int r1 = min(max(y0 + 1, 0), Hh - 1);
    int c0 = min(max(x0, 0), Ww - 1);
    int c1 = min(max(x0 + 1, 0), Ww - 1);
    float w00 = (1.f - wy) * (1.f - wx) * vy0 * vx0;
    float w01 = (1.f - wy) * wx * vy0 * vx1;
    float w10 = wy * (1.f - wx) * vy1 * vx0;
    float w11 = wy * wx * vy1 * vx1;
    uint4 D;
    D.x = (unsigned int)((r0 * Ww + c0) * 128);
    D.y = (unsigned int)((c1 - c0) * 128) |
          ((unsigned int)((r1 - r0) * Ww * 128) << 16);
    D.z = f2h2u(w00, w01);
    D.w = f2h2u(w10, w11);
    gdesc[e] = D;
  }
  __syncthreads();

  // ---- pipeline state (persistent registers) ----
  uint4 gA[8], gB[8];        // gather batches: gA holds even-kk, gB odd-kk
  half8 wfA[2][3], wfB[2][3];  // weight sets: wfA even-kk, wfB odd-kk

  // ---- prologue ----
  // wf(kk=0) -> wfA; gathers(kk=0) -> gA; combine kk=0 (one exposed wait);
  // gathers(kk=1) -> gB; wf(kk=1) -> wfB (stay in flight across barrier).
#pragma unroll
  for (int ch = 0; ch < 2; ch++)
#pragma unroll
    for (int j = 0; j < 3; j++) {
      int nt = j * 4 + wv;
      wfA[ch][j] =
          *(const half8*)&bfrag[((size_t)(ch * 12 + nt) * 64 + l) * 8];
    }
  {
    uint4 D0 = gdesc[pl0], D1 = gdesc[pl1];
    gather_issue(gbase, D0, chB, gA[0], gA[1], gA[2], gA[3]);
    gather_issue(gbase, D1, chB, gA[4], gA[5], gA[6], gA[7]);
    combine_write(&A[0][pl0 * AST + ch8 * 8], make_uint2(D0.z, D0.w), gA[0],
                  gA[1], gA[2], gA[3]);
    combine_write(&A[0][pl1 * AST + ch8 * 8], make_uint2(D1.z, D1.w), gA[4],
                  gA[5], gA[6], gA[7]);
    uint4 E0 = gdesc[64 + pl0], E1 = gdesc[64 + pl1];
    gather_issue(gbase, E0, chB, gB[0], gB[1], gB[2], gB[3]);
    gather_issue(gbase, E1, chB, gB[4], gB[5], gB[6], gB[7]);
  }
#pragma unroll
  for (int ch = 0; ch < 2; ch++)
#pragma unroll
    for (int j = 0; j < 3; j++) {
      int nt = j * 4 + wv;
      wfB[ch][j] =
          *(const half8*)&bfrag[((size_t)((2 + ch) * 12 + nt) * 64 + l) * 8];
    }
  asm volatile("s_waitcnt lgkmcnt(0)" ::: "memory");
  __builtin_amdgcn_s_barrier();

#pragma unroll
  for (int kk = 0; kk < 9; kk++) {
    const int cur = kk & 1;
    // 1) MFMA(kk) on A[cur]; weights wf(kk) loaded two phases ago -> the
    //    vmcnt wait leaves last phase's 14 loads outstanding (counted).
#pragma unroll
    for (int chunk = 0; chunk < 2; chunk++) {
      half8 sfr[4];
#pragma unroll
      for (int pt = 0; pt < 4; pt++)
        sfr[pt] = *(const half8*)&A[cur][(pt * 16 + lm) * AST + chunk * 32 +
                                         quad * 8];
      if (cur == 0) {
#pragma unroll
        for (int j = 0; j < 3; j++)
#pragma unroll
          for (int pt = 0; pt < 4; pt++)
            acc[j][pt] = __builtin_amdgcn_mfma_f32_16x16x32_f16(
                wfA[chunk][j], sfr[pt], acc[j][pt], 0, 0, 0);
      } else {
#pragma unroll
        for (int j = 0; j < 3; j++)
#pragma unroll
          for (int pt = 0; pt < 4; pt++)
            acc[j][pt] = __builtin_amdgcn_mfma_f32_16x16x32_f16(
                wfB[chunk][j], sfr[pt], acc[j][pt], 0, 0, 0);
      }
    }
    // 2) combine(kk+1): gathers issued last phase (before last phase's wf
    //    loads) -> wait is vmcnt(6), cover = barrier + full MFMA section.
    if (kk < 8) {
      uint2 W0 = gdw[((kk + 1) * 64 + pl0) * 2 + 1];
      uint2 W1 = gdw[((kk + 1) * 64 + pl1) * 2 + 1];
      unsigned short* d0 = &A[cur ^ 1][pl0 * AST + ch8 * 8];
      unsigned short* d1 = &A[cur ^ 1][pl1 * AST + ch8 * 8];
      if (cur == 0) {
        combine_write(d0, W0, gB[0], gB[1], gB[2], gB[3]);
        combine_write(d1, W1, gB[4], gB[5], gB[6], gB[7]);
      } else {
        combine_write(d0, W0, gA[0], gA[1], gA[2], gA[3]);
        combine_write(d1, W1, gA[4], gA[5], gA[6], gA[7]);
      }
    }
    // 3) issue gathers(kk+2) into the batch just freed by last phase's
    //    combine; 4) load wf(kk+2) into the set just consumed by MFMA(kk).
    //    Both stay in flight across the lgkm-only barrier.
    if (kk < 7) {
      uint4 D0 = gdesc[(kk + 2) * 64 + pl0];
      uint4 D1 = gdesc[(kk + 2) * 64 + pl1];
      if (cur == 0) {
        gather_issue(gbase, D0, chB, gA[0], gA[1], gA[2], gA[3]);
        gather_issue(gbase, D1, chB, gA[4], gA[5], gA[6], gA[7]);
      } else {
        gather_issue(gbase, D0, chB, gB[0], gB[1], gB[2], gB[3]);
        gather_issue(gbase, D1, chB, gB[4], gB[5], gB[6], gB[7]);
      }
#pragma unroll
      for (int ch = 0; ch < 2; ch++)
#pragma unroll
        for (int j = 0; j < 3; j++) {
          int nt = j * 4 + wv;
          half8 v = *(const half8*)&bfrag[((size_t)(((kk + 2) * 2 + ch) * 12 +
                                                    nt) * 64 + l) * 8];
          if (cur == 0)
            wfA[ch][j] = v;
          else
            wfB[ch][j] = v;
        }
    }
    if (kk < 8) {
      asm volatile("s_waitcnt lgkmcnt(0)" ::: "memory");
      __builtin_amdgcn_s_barrier();
    }
  }

  // ---- epilogue: out = (pm + w0) / (1 + |qn0| + |qn1|) ----
  float w0v[4];
#pragma unroll
  for (int r = 0; r < 4; r++) w0v[r] = w0[wv * 16 + quad * 4 + r];
  float* ob = out + (size_t)b * Cc * HWc + pix0;
#pragma unroll
  for (int pt = 0; pt < 4; pt++) {
#pragma unroll
    for (int r = 0; r < 4; r++) {
      int oc = wv * 16 + quad * 4 + r;
      float pm = acc[0][pt][r] + w0v[r];
      float qn = 1.0f + fabsf(acc[1][pt][r]) + fabsf(acc[2][pt][r]);
      ob[oc * HWc + pt * 16 + lm] = pm / qn;
    }
  }
}

extern "C" void kernel_launch(void* const* d_in, const int* in_sizes, int n_in,
                              void* d_out, int out_size, void* d_ws, size_t ws_size,
                              hipStream_t stream) {
  const float* x = (const float*)d_in[0];      // [4,64,160,160]
  const float* off_w = (const float*)d_in[1];  // [18,64]
  const float* off_b = (const float*)d_in[2];  // [18]
  const float* w_m = (const float*)d_in[3];    // [128,64,3,3]
  const float* w_n = (const float*)d_in[4];    // [128,64,3,3]
  const float* w0 = (const float*)d_in[5];     // [64]
  float* out = (float*)d_out;                  // [4,64,160,160]

  // ws layout: bfrag 221184 B | obfrag 4096 B | xT 13107200 B  (~13.3 MB)
  unsigned short* bfrag = (unsigned short*)d_ws;
  unsigned short* obfrag = (unsigned short*)((char*)d_ws + (size_t)221184);
  unsigned short* xT = (unsigned short*)((char*)d_ws + (size_t)225280);

  hipLaunchKernelGGL(k_prep, dim3(840), dim3(256), 0, stream, x, w_m, w_n,
                     off_w, xT, bfrag);
  hipLaunchKernelGGL(k_main, dim3(1600), dim3(256), 0, stream, xT, w0, off_b,
                     bfrag, obfrag, out);
}

// Round 7
// 128.167 us; speedup vs baseline: 1.1179x; 1.0247x over previous
//
#include <hip/hip_runtime.h>
#include <hip/hip_bf16.h>
#include <hip/hip_fp16.h>

#define Hh 160
#define Ww 160
#define Cc 64
#define HWc 25600
#define Bb 4
#define AST 68  // A-tile row stride in halves (136B). R7: 76->68 shrinks LDS
                // 28672->26624 B => 6 blocks/CU (was 5). Pure-TLP A/B vs R0:
                // registers, descriptors, schedule all byte-identical.

typedef __attribute__((ext_vector_type(8))) _Float16 half8;
typedef __attribute__((ext_vector_type(4))) float f32x4;

__device__ __forceinline__ unsigned int f2h2u(float a, float b) {
  __half2 h = __floats2half2_rn(a, b);
  return *(unsigned int*)&h;
}

// ---------------------------------------------------------------------------
// Kernel P: role-split prep (unchanged).
// ---------------------------------------------------------------------------
__global__ __launch_bounds__(256) void k_prep(
    const float* __restrict__ x, const float* __restrict__ wm,
    const float* __restrict__ wn, const float* __restrict__ ow,
    unsigned short* __restrict__ xT, unsigned short* __restrict__ bf) {
  if (blockIdx.x < 400) {
    __shared__ unsigned short s[64][260];
    int wg = blockIdx.x;  // 400 = 4b * 100
    int b = wg / 100;
    int pix0 = (wg % 100) * 256;
    int l = threadIdx.x & 63, wv = threadIdx.x >> 6;
    const float* xb = x + (size_t)b * Cc * HWc + pix0;
#pragma unroll
    for (int i = 0; i < 16; i++) {
      int c = i * 4 + wv;
      float4 v = *(const float4*)&xb[(size_t)c * HWc + l * 4];
      *(uint2*)&s[c][l * 4] = make_uint2(f2h2u(v.x, v.y), f2h2u(v.z, v.w));
    }
    __syncthreads();
    int p = threadIdx.x;  // pixel 0..255
    unsigned int w[32];
#pragma unroll
    for (int j = 0; j < 32; j++) {
      unsigned int a = s[2 * j][p];
      unsigned int bb = s[2 * j + 1][p];
      w[j] = (a & 0xffffu) | (bb << 16);
    }
    unsigned short* dst = xT + ((size_t)(b * HWc + pix0 + p)) * 64;
#pragma unroll
    for (int j = 0; j < 8; j++)
      ((uint4*)dst)[j] = make_uint4(w[4 * j], w[4 * j + 1], w[4 * j + 2], w[4 * j + 3]);
  } else {
    int i = (blockIdx.x - 400) * 256 + threadIdx.x;
    if (i < 9 * 2 * 12 * 64 * 8) {
      int j2 = i & 7;
      int lane = (i >> 3) & 63;
      int ntck = i >> 9;
      int nt = ntck % 12;
      int ck = ntck / 12;
      int kk = ck >> 1;
      int chunk = ck & 1;
      int n = nt * 16 + (lane & 15);
      int c = chunk * 32 + (lane >> 4) * 8 + j2;
      float v;
      if (n < 64)
        v = wm[(n * 64 + c) * 9 + kk] + wm[((n + 64) * 64 + c) * 9 + kk];
      else
        v = wn[((n - 64) * 64 + c) * 9 + kk];
      __half hv = __float2half_rn(v);
      bf[i] = *(unsigned short*)&hv;
    } else if (i < 9 * 2 * 12 * 64 * 8 + 2 * 2 * 64 * 8) {
      int j = i - 9 * 2 * 12 * 64 * 8;
      int j2 = j & 7;
      int lane = (j >> 3) & 63;
      int rest = j >> 9;  // chunk*2 + ntile
      int ntile = rest & 1;
      int chunk = rest >> 1;
      int n = ntile * 16 + (lane & 15);
      int c = chunk * 32 + (lane >> 4) * 8 + j2;
      if (n < 18) {
        __half hv = __float2half_rn(ow[n * 64 + c]);
        bf[i] = *(unsigned short*)&hv;
      } else {
        bf[i] = 0;
      }
    }
  }
}

// ---------------------------------------------------------------------------
// Kernel M: exact R0 structure (empirical optimum over 6 controlled rounds:
// scheduling/MLP/ILP variants all regressed via spill, lost gather-MLP, or
// lost TLP). Only change vs R0: AST 76->68 => 6 blocks/CU instead of 5.
// ---------------------------------------------------------------------------
__device__ __forceinline__ void gather2h(const char* __restrict__ gbase, uint4 D,
                                         int chB, uint4& c00, uint4& c01,
                                         uint4& c10, uint4& c11, __half2& W00,
                                         __half2& W01, __half2& W10,
                                         __half2& W11) {
  int bb = (int)D.x + chB;
  int dxB = (int)(D.y & 0xffffu);
  int dyB = (int)(D.y >> 16);
  c00 = *(const uint4*)(gbase + bb);
  c01 = *(const uint4*)(gbase + bb + dxB);
  c10 = *(const uint4*)(gbase + bb + dyB);
  c11 = *(const uint4*)(gbase + bb + dxB + dyB);
  __half2 wz = *(const __half2*)&D.z;
  __half2 ww = *(const __half2*)&D.w;
  W00 = __half2half2(__low2half(wz));
  W01 = __half2half2(__high2half(wz));
  W10 = __half2half2(__low2half(ww));
  W11 = __half2half2(__high2half(ww));
}

__device__ __forceinline__ void combine_write(unsigned short* Arow,
                                              const uint4& c00, const uint4& c01,
                                              const uint4& c10, const uint4& c11,
                                              __half2 W00, __half2 W01,
                                              __half2 W10, __half2 W11) {
  const unsigned int* a = (const unsigned int*)&c00;
  const unsigned int* b = (const unsigned int*)&c01;
  const unsigned int* c = (const unsigned int*)&c10;
  const unsigned int* d = (const unsigned int*)&c11;
  unsigned int o[4];
#pragma unroll
  for (int j = 0; j < 4; j++) {
    __half2 ha = *(const __half2*)&a[j];
    __half2 hb = *(const __half2*)&b[j];
    __half2 hc = *(const __half2*)&c[j];
    __half2 hd = *(const __half2*)&d[j];
    __half2 r = __hfma2(ha, W00,
                        __hfma2(hb, W01, __hfma2(hc, W10, __hmul2(hd, W11))));
    o[j] = *(unsigned int*)&r;
  }
  *(uint4*)Arow = make_uint4(o[0], o[1], o[2], o[3]);
}

__global__ __launch_bounds__(256, 4) void k_main(
    const unsigned short* __restrict__ xT, const float* __restrict__ w0,
    const float* __restrict__ off_b, const unsigned short* __restrict__ bfrag,
    const unsigned short* __restrict__ obfrag, float* __restrict__ out) {
  __shared__ unsigned short A[2][64 * AST];  // [buf][px][c], f16
  __shared__ uint4 gdesc[576];               // per (kk,px) gather descriptor
  float2* spy = (float2*)&A[0][0];           // overlay, dead after desc build
  const int tid = threadIdx.x;
  const int wg = blockIdx.x;  // 1600
  const int band = wg & 7;    // XCD id under round-robin
  const int local = wg >> 3;  // 0..199
  const int b = local / 50;
  const int pix0 = band * 3200 + (local % 50) * 64;
  const int wv = tid >> 6;
  const int l = tid & 63;
  const int lm = l & 15;
  const int quad = l >> 4;
  const int ch8 = l & 7;  // channel octet (16 B)
  const int pr = l >> 3;  // pixel-in-batch 0..7
  const int chB = ch8 * 16;

  const unsigned short* xTb = xT + (size_t)b * HWc * 64;
  const char* gbase = (const char*)xTb;

  f32x4 acc[3][4];
  const f32x4 zero = {0.f, 0.f, 0.f, 0.f};
#pragma unroll
  for (int j = 0; j < 3; j++)
#pragma unroll
    for (int pt = 0; pt < 4; pt++) acc[j][pt] = zero;

  // ---- phase 0: offsets via MFMA -> spy (overlay) ----
  {
    f32x4 aO0 = zero, aO1 = zero;
    const unsigned short* xrow = xTb + (size_t)(pix0 + wv * 16 + lm) * 64;
#pragma unroll
    for (int chunk = 0; chunk < 2; chunk++) {
      half8 sb = *(const half8*)(xrow + chunk * 32 + quad * 8);
      half8 wf0 = *(const half8*)&obfrag[((chunk * 2 + 0) * 64 + l) * 8];
      half8 wf1 = *(const half8*)&obfrag[((chunk * 2 + 1) * 64 + l) * 8];
      aO0 = __builtin_amdgcn_mfma_f32_16x16x32_f16(wf0, sb, aO0, 0, 0, 0);
      aO1 = __builtin_amdgcn_mfma_f32_16x16x32_f16(wf1, sb, aO1, 0, 0, 0);
    }
    int pix = pix0 + wv * 16 + lm;
    int h = pix / Ww, w = pix % Ww;
    float fh = (float)h, fw = (float)w;
#pragma unroll
    for (int rr = 0; rr < 2; rr++) {
      int n = quad * 4 + 2 * rr;
      int kk = n >> 1;
      float oy = aO0[2 * rr] + off_b[n];
      float ox = aO0[2 * rr + 1] + off_b[n + 1];
      oy = fminf(fmaxf(oy, -fh), 160.0f - fh);
      ox = fminf(fmaxf(ox, -fw), 160.0f - fw);
      if (fabsf(oy) >= 8.0f) oy = 8.0f * tanhf(oy * 0.125f);
      if (fabsf(ox) >= 8.0f) ox = 8.0f * tanhf(ox * 0.125f);
      spy[kk * 64 + wv * 16 + lm] =
          make_float2(fh - 1.0f + (float)(kk / 3) + oy,
                      fw - 1.0f + (float)(kk % 3) + ox);
    }
    if (quad == 0) {  // kk=8 from tile1 rows 16,17
      float oy = aO1[0] + off_b[16];
      float ox = aO1[1] + off_b[17];
      oy = fminf(fmaxf(oy, -fh), 160.0f - fh);
      ox = fminf(fmaxf(ox, -fw), 160.0f - fw);
      if (fabsf(oy) >= 8.0f) oy = 8.0f * tanhf(oy * 0.125f);
      if (fabsf(ox) >= 8.0f) ox = 8.0f * tanhf(ox * 0.125f);
      spy[8 * 64 + wv * 16 + lm] =
          make_float2(fh + 1.0f + oy, fw + 1.0f + ox);
    }
  }
  __syncthreads();

  // ---- descriptor build: 576 entries over 256 threads ----
  for (int e = tid; e < 576; e += 256) {
    float2 P = spy[e];
    float py = P.x, pxv = P.y;
    float y0f = floorf(py), x0f = floorf(pxv);
    float wy = py - y0f, wx = pxv - x0f;
    int y0 = (int)y0f, x0 = (int)x0f;
    float vy0 = (y0 >= 0 && y0 < Hh) ? 1.f : 0.f;
    float vy1 = (y0 >= -1 && y0 < Hh - 1) ? 1.f : 0.f;
    float vx0 = (x0 >= 0 && x0 < Ww) ? 1.f : 0.f;
    float vx1 = (x0 >= -1 && x0 < Ww - 1) ? 1.f : 0.f;
    int r0 = min(max(y0, 0), Hh - 1);
    int r1 = min(max(y0 + 1, 0), Hh - 1);
    int c0 = min(max(x0, 0), Ww - 1);
    int c1 = min(max(x0 + 1, 0), Ww - 1);
    float w00 = (1.f - wy) * (1.f - wx) * vy0 * vx0;
    float w01 = (1.f - wy) * wx * vy0 * vx1;
    float w10 = wy * (1.f - wx) * vy1 * vx0;
    float w11 = wy * wx * vy1 * vx1;
    uint4 D;
    D.x = (unsigned int)((r0 * Ww + c0) * 128);
    D.y = (unsigned int)((c1 - c0) * 128) |
          ((unsigned int)((r1 - r0) * Ww * 128) << 16);
    D.z = f2h2u(w00, w01);
    D.w = f2h2u(w10, w11);
    gdesc[e] = D;
  }
  __syncthreads();

  // ---- prologue: gather kk=0 into buf 0 ----
#pragma unroll
  for (int i = 0; i < 2; i++) {
    int pl = wv * 16 + i * 8 + pr;
    uint4 c00, c01, c10, c11;
    __half2 W00, W01, W10, W11;
    gather2h(gbase, gdesc[pl], chB, c00, c01, c10, c11, W00, W01, W10, W11);
    combine_write(&A[0][pl * AST + ch8 * 8], c00, c01, c10, c11, W00, W01, W10,
                  W11);
  }
  __syncthreads();

  for (int kk = 0; kk < 9; kk++) {
    const int cur = kk & 1;
    uint4 g00[2], g01[2], g10[2], g11[2];
    __half2 W00[2], W01[2], W10[2], W11[2];
    if (kk < 8) {  // issue next-kk gathers; latency hides behind MFMA phase
#pragma unroll
      for (int i = 0; i < 2; i++) {
        int pl = wv * 16 + i * 8 + pr;
        gather2h(gbase, gdesc[(kk + 1) * 64 + pl], chB, g00[i], g01[i], g10[i],
                 g11[i], W00[i], W01[i], W10[i], W11[i]);
      }
    }
    // MFMA on current buffer
#pragma unroll
    for (int chunk = 0; chunk < 2; chunk++) {
      half8 sfr[4];
#pragma unroll
      for (int pt = 0; pt < 4; pt++)
        sfr[pt] = *(const half8*)&A[cur][(pt * 16 + lm) * AST + chunk * 32 +
                                         quad * 8];
      half8 wfr[3];
#pragma unroll
      for (int j = 0; j < 3; j++) {
        int nt = j * 4 + wv;
        wfr[j] = *(const half8*)&bfrag[((size_t)((kk * 2 + chunk) * 12 + nt) *
                                           64 + l) * 8];
      }
#pragma unroll
      for (int j = 0; j < 3; j++)
#pragma unroll
        for (int pt = 0; pt < 4; pt++)
          acc[j][pt] = __builtin_amdgcn_mfma_f32_16x16x32_f16(
              wfr[j], sfr[pt], acc[j][pt], 0, 0, 0);
    }
    if (kk < 8) {
#pragma unroll
      for (int i = 0; i < 2; i++) {
        int pl = wv * 16 + i * 8 + pr;
        combine_write(&A[cur ^ 1][pl * AST + ch8 * 8], g00[i], g01[i], g10[i],
                      g11[i], W00[i], W01[i], W10[i], W11[i]);
      }
    }
    __syncthreads();
  }

  // ---- epilogue: out = (pm + w0) / (1 + |qn0| + |qn1|) ----
  float w0v[4];
#pragma unroll
  for (int r = 0; r < 4; r++) w0v[r] = w0[wv * 16 + quad * 4 + r];
  float* ob = out + (size_t)b * Cc * HWc + pix0;
#pragma unroll
  for (int pt = 0; pt < 4; pt++) {
#pragma unroll
    for (int r = 0; r < 4; r++) {
      int oc = wv * 16 + quad * 4 + r;
      float pm = acc[0][pt][r] + w0v[r];
      float qn = 1.0f + fabsf(acc[1][pt][r]) + fabsf(acc[2][pt][r]);
      ob[oc * HWc + pt * 16 + lm] = pm / qn;
    }
  }
}

extern "C" void kernel_launch(void* const* d_in, const int* in_sizes, int n_in,
                              void* d_out, int out_size, void* d_ws, size_t ws_size,
                              hipStream_t stream) {
  const float* x = (const float*)d_in[0];      // [4,64,160,160]
  const float* off_w = (const float*)d_in[1];  // [18,64]
  const float* off_b = (const float*)d_in[2];  // [18]
  const float* w_m = (const float*)d_in[3];    // [128,64,3,3]
  const float* w_n = (const float*)d_in[4];    // [128,64,3,3]
  const float* w0 = (const float*)d_in[5];     // [64]
  float* out = (float*)d_out;                  // [4,64,160,160]

  // ws layout: bfrag 221184 B | obfrag 4096 B | xT 13107200 B  (~13.3 MB)
  unsigned short* bfrag = (unsigned short*)d_ws;
  unsigned short* obfrag = (unsigned short*)((char*)d_ws + (size_t)221184);
  unsigned short* xT = (unsigned short*)((char*)d_ws + (size_t)225280);

  hipLaunchKernelGGL(k_prep, dim3(840), dim3(256), 0, stream, x, w_m, w_n,
                     off_w, xT, bfrag);
  hipLaunchKernelGGL(k_main, dim3(1600), dim3(256), 0, stream, xT, w0, off_b,
                     bfrag, obfrag, out);
}

// Round 8
// 128.148 us; speedup vs baseline: 1.1180x; 1.0002x over previous
//
#include <hip/hip_runtime.h>
#include <hip/hip_bf16.h>
#include <hip/hip_fp16.h>

#define Hh 160
#define Ww 160
#define Cc 64
#define HWc 25600
#define Bb 4
#define AST 76  // A-tile row stride in halves (152B): sfr ds_read_b128 bank
                // map (6*lm+4*quad)%32 = 16 distinct banks -> 2-way (free).
                // R7's AST=68 gave (2*lm+4*quad)%32 -> 4-way, +2us. Keep 76.

typedef __attribute__((ext_vector_type(8))) _Float16 half8;
typedef __attribute__((ext_vector_type(4))) float f32x4;

__device__ __forceinline__ unsigned int f2h2u(float a, float b) {
  __half2 h = __floats2half2_rn(a, b);
  return *(unsigned int*)&h;
}

// ---------------------------------------------------------------------------
// Kernel P: role-split prep (unchanged).
// ---------------------------------------------------------------------------
__global__ __launch_bounds__(256) void k_prep(
    const float* __restrict__ x, const float* __restrict__ wm,
    const float* __restrict__ wn, const float* __restrict__ ow,
    unsigned short* __restrict__ xT, unsigned short* __restrict__ bf) {
  if (blockIdx.x < 400) {
    __shared__ unsigned short s[64][260];
    int wg = blockIdx.x;  // 400 = 4b * 100
    int b = wg / 100;
    int pix0 = (wg % 100) * 256;
    int l = threadIdx.x & 63, wv = threadIdx.x >> 6;
    const float* xb = x + (size_t)b * Cc * HWc + pix0;
#pragma unroll
    for (int i = 0; i < 16; i++) {
      int c = i * 4 + wv;
      float4 v = *(const float4*)&xb[(size_t)c * HWc + l * 4];
      *(uint2*)&s[c][l * 4] = make_uint2(f2h2u(v.x, v.y), f2h2u(v.z, v.w));
    }
    __syncthreads();
    int p = threadIdx.x;  // pixel 0..255
    unsigned int w[32];
#pragma unroll
    for (int j = 0; j < 32; j++) {
      unsigned int a = s[2 * j][p];
      unsigned int bb = s[2 * j + 1][p];
      w[j] = (a & 0xffffu) | (bb << 16);
    }
    unsigned short* dst = xT + ((size_t)(b * HWc + pix0 + p)) * 64;
#pragma unroll
    for (int j = 0; j < 8; j++)
      ((uint4*)dst)[j] = make_uint4(w[4 * j], w[4 * j + 1], w[4 * j + 2], w[4 * j + 3]);
  } else {
    int i = (blockIdx.x - 400) * 256 + threadIdx.x;
    if (i < 9 * 2 * 12 * 64 * 8) {
      int j2 = i & 7;
      int lane = (i >> 3) & 63;
      int ntck = i >> 9;
      int nt = ntck % 12;
      int ck = ntck / 12;
      int kk = ck >> 1;
      int chunk = ck & 1;
      int n = nt * 16 + (lane & 15);
      int c = chunk * 32 + (lane >> 4) * 8 + j2;
      float v;
      if (n < 64)
        v = wm[(n * 64 + c) * 9 + kk] + wm[((n + 64) * 64 + c) * 9 + kk];
      else
        v = wn[((n - 64) * 64 + c) * 9 + kk];
      __half hv = __float2half_rn(v);
      bf[i] = *(unsigned short*)&hv;
    } else if (i < 9 * 2 * 12 * 64 * 8 + 2 * 2 * 64 * 8) {
      int j = i - 9 * 2 * 12 * 64 * 8;
      int j2 = j & 7;
      int lane = (j >> 3) & 63;
      int rest = j >> 9;  // chunk*2 + ntile
      int ntile = rest & 1;
      int chunk = rest >> 1;
      int n = ntile * 16 + (lane & 15);
      int c = chunk * 32 + (lane >> 4) * 8 + j2;
      if (n < 18) {
        __half hv = __float2half_rn(ow[n * 64 + c]);
        bf[i] = *(unsigned short*)&hv;
      } else {
        bf[i] = 0;
      }
    }
  }
}

// ---------------------------------------------------------------------------
// Kernel M. R8: exact R0 structure; ONE zero-structure change = VMEM ISSUE
// ORDER. vmcnt retires in order, so R0's order (gathers then weights) made
// the MFMA's weight-wait an effective vmcnt(0) that drained the just-issued
// gathers every phase (~400cy exposed, barrier-locked). Now ALL 6 weight
// fragments issue FIRST, then the 8 gathers: MFMA's weight-wait = vmcnt(8)
// (gathers stay in flight through the whole MFMA section); combine's
// vmcnt(0) lands on near-complete loads. Register budget kept <=128 by
// deferring the bilinear-weight unpack to combine (re-read D.zw from gdesc
// LDS, the R4/R5-proven gdw pattern): peak live ~126.
// R2/R5 tested this theory but were confounded by scratch spill; this is
// the clean A/B.
// ---------------------------------------------------------------------------
__device__ __forceinline__ void gather_issue(const char* __restrict__ gbase,
                                             uint4 D, int chB, uint4& c00,
                                             uint4& c01, uint4& c10,
                                             uint4& c11) {
  int bb = (int)D.x + chB;
  int dxB = (int)(D.y & 0xffffu);
  int dyB = (int)(D.y >> 16);
  c00 = *(const uint4*)(gbase + bb);
  c01 = *(const uint4*)(gbase + bb + dxB);
  c10 = *(const uint4*)(gbase + bb + dyB);
  c11 = *(const uint4*)(gbase + bb + dxB + dyB);
}

__device__ __forceinline__ void combine_write(unsigned short* Arow, uint2 Wzw,
                                              const uint4& c00, const uint4& c01,
                                              const uint4& c10,
                                              const uint4& c11) {
  __half2 wz = *(const __half2*)&Wzw.x;
  __half2 ww = *(const __half2*)&Wzw.y;
  __half2 W00 = __half2half2(__low2half(wz));
  __half2 W01 = __half2half2(__high2half(wz));
  __half2 W10 = __half2half2(__low2half(ww));
  __half2 W11 = __half2half2(__high2half(ww));
  const unsigned int* a = (const unsigned int*)&c00;
  const unsigned int* b = (const unsigned int*)&c01;
  const unsigned int* c = (const unsigned int*)&c10;
  const unsigned int* d = (const unsigned int*)&c11;
  unsigned int o[4];
#pragma unroll
  for (int j = 0; j < 4; j++) {
    __half2 ha = *(const __half2*)&a[j];
    __half2 hb = *(const __half2*)&b[j];
    __half2 hc = *(const __half2*)&c[j];
    __half2 hd = *(const __half2*)&d[j];
    __half2 r = __hfma2(ha, W00,
                        __hfma2(hb, W01, __hfma2(hc, W10, __hmul2(hd, W11))));
    o[j] = *(unsigned int*)&r;
  }
  *(uint4*)Arow = make_uint4(o[0], o[1], o[2], o[3]);
}

__global__ __launch_bounds__(256, 4) void k_main(
    const unsigned short* __restrict__ xT, const float* __restrict__ w0,
    const float* __restrict__ off_b, const unsigned short* __restrict__ bfrag,
    const unsigned short* __restrict__ obfrag, float* __restrict__ out) {
  __shared__ unsigned short A[2][64 * AST];  // [buf][px][c], f16
  __shared__ uint4 gdesc[576];               // per (kk,px) gather descriptor
  float2* spy = (float2*)&A[0][0];           // overlay, dead after desc build
  const uint2* gdw = (const uint2*)gdesc;    // .zw view: index e*2+1
  const int tid = threadIdx.x;
  const int wg = blockIdx.x;  // 1600
  const int band = wg & 7;    // XCD id under round-robin
  const int local = wg >> 3;  // 0..199
  const int b = local / 50;
  const int pix0 = band * 3200 + (local % 50) * 64;
  const int wv = tid >> 6;
  const int l = tid & 63;
  const int lm = l & 15;
  const int quad = l >> 4;
  const int ch8 = l & 7;  // channel octet (16 B)
  const int pr = l >> 3;  // pixel-in-batch 0..7
  const int chB = ch8 * 16;

  const unsigned short* xTb = xT + (size_t)b * HWc * 64;
  const char* gbase = (const char*)xTb;

  f32x4 acc[3][4];
  const f32x4 zero = {0.f, 0.f, 0.f, 0.f};
#pragma unroll
  for (int j = 0; j < 3; j++)
#pragma unroll
    for (int pt = 0; pt < 4; pt++) acc[j][pt] = zero;

  // ---- phase 0: offsets via MFMA -> spy (overlay) ----
  {
    f32x4 aO0 = zero, aO1 = zero;
    const unsigned short* xrow = xTb + (size_t)(pix0 + wv * 16 + lm) * 64;
#pragma unroll
    for (int chunk = 0; chunk < 2; chunk++) {
      half8 sb = *(const half8*)(xrow + chunk * 32 + quad * 8);
      half8 wf0 = *(const half8*)&obfrag[((chunk * 2 + 0) * 64 + l) * 8];
      half8 wf1 = *(const half8*)&obfrag[((chunk * 2 + 1) * 64 + l) * 8];
      aO0 = __builtin_amdgcn_mfma_f32_16x16x32_f16(wf0, sb, aO0, 0, 0, 0);
      aO1 = __builtin_amdgcn_mfma_f32_16x16x32_f16(wf1, sb, aO1, 0, 0, 0);
    }
    int pix = pix0 + wv * 16 + lm;
    int h = pix / Ww, w = pix % Ww;
    float fh = (float)h, fw = (float)w;
#pragma unroll
    for (int rr = 0; rr < 2; rr++) {
      int n = quad * 4 + 2 * rr;
      int kk = n >> 1;
      float oy = aO0[2 * rr] + off_b[n];
      float ox = aO0[2 * rr + 1] + off_b[n + 1];
      oy = fminf(fmaxf(oy, -fh), 160.0f - fh);
      ox = fminf(fmaxf(ox, -fw), 160.0f - fw);
      if (fabsf(oy) >= 8.0f) oy = 8.0f * tanhf(oy * 0.125f);
      if (fabsf(ox) >= 8.0f) ox = 8.0f * tanhf(ox * 0.125f);
      spy[kk * 64 + wv * 16 + lm] =
          make_float2(fh - 1.0f + (float)(kk / 3) + oy,
                      fw - 1.0f + (float)(kk % 3) + ox);
    }
    if (quad == 0) {  // kk=8 from tile1 rows 16,17
      float oy = aO1[0] + off_b[16];
      float ox = aO1[1] + off_b[17];
      oy = fminf(fmaxf(oy, -fh), 160.0f - fh);
      ox = fminf(fmaxf(ox, -fw), 160.0f - fw);
      if (fabsf(oy) >= 8.0f) oy = 8.0f * tanhf(oy * 0.125f);
      if (fabsf(ox) >= 8.0f) ox = 8.0f * tanhf(ox * 0.125f);
      spy[8 * 64 + wv * 16 + lm] =
          make_float2(fh + 1.0f + oy, fw + 1.0f + ox);
    }
  }
  __syncthreads();

  // ---- descriptor build: 576 entries over 256 threads ----
  for (int e = tid; e < 576; e += 256) {
    float2 P = spy[e];
    float py = P.x, pxv = P.y;
    float y0f = floorf(py), x0f = floorf(pxv);
    float wy = py - y0f, wx = pxv - x0f;
    int y0 = (int)y0f, x0 = (int)x0f;
    float vy0 = (y0 >= 0 && y0 < Hh) ? 1.f : 0.f;
    float vy1 = (y0 >= -1 && y0 < Hh - 1) ? 1.f : 0.f;
    float vx0 = (x0 >= 0 && x0 < Ww) ? 1.f : 0.f;
    float vx1 = (x0 >= -1 && x0 < Ww - 1) ? 1.f : 0.f;
    int r0 = min(max(y0, 0), Hh - 1);
    int r1 = min(max(y0 + 1, 0), Hh - 1);
    int c0 = min(max(x0, 0), Ww - 1);
    int c1 = min(max(x0 + 1, 0), Ww - 1);
    float w00 = (1.f - wy) * (1.f - wx) * vy0 * vx0;
    float w01 = (1.f - wy) * wx * vy0 * vx1;
    float w10 = wy * (1.f - wx) * vy1 * vx0;
    float w11 = wy * wx * vy1 * vx1;
    uint4 D;
    D.x = (unsigned int)((r0 * Ww + c0) * 128);
    D.y = (unsigned int)((c1 - c0) * 128) |
          ((unsigned int)((r1 - r0) * Ww * 128) << 16);
    D.z = f2h2u(w00, w01);
    D.w = f2h2u(w10, w11);
    gdesc[e] = D;
  }
  __syncthreads();

  // ---- prologue: gather+combine kk=0 into buf 0 ----
#pragma unroll
  for (int i = 0; i < 2; i++) {
    int pl = wv * 16 + i * 8 + pr;
    uint4 c00, c01, c10, c11;
    gather_issue(gbase, gdesc[pl], chB, c00, c01, c10, c11);
    combine_write(&A[0][pl * AST + ch8 * 8], gdw[pl * 2 + 1], c00, c01, c10,
                  c11);
  }
  __syncthreads();

  for (int kk = 0; kk < 9; kk++) {
    const int cur = kk & 1;
    // (1) ALL weight fragments for this kk issue FIRST (oldest in FIFO).
    half8 wfr[2][3];
#pragma unroll
    for (int chunk = 0; chunk < 2; chunk++)
#pragma unroll
      for (int j = 0; j < 3; j++) {
        int nt = j * 4 + wv;
        wfr[chunk][j] =
            *(const half8*)&bfrag[((size_t)((kk * 2 + chunk) * 12 + nt) * 64 +
                                   l) * 8];
      }
    // (2) next-kk gathers issue AFTER (youngest): the MFMA weight-wait is
    // then a counted vmcnt that leaves these 8 loads in flight.
    uint4 g00[2], g01[2], g10[2], g11[2];
    if (kk < 8) {
#pragma unroll
      for (int i = 0; i < 2; i++) {
        int pl = wv * 16 + i * 8 + pr;
        gather_issue(gbase, gdesc[(kk + 1) * 64 + pl], chB, g00[i], g01[i],
                     g10[i], g11[i]);
      }
    }
    // (3) MFMA on current buffer; weight-wait = vmcnt(8), gathers in flight.
#pragma unroll
    for (int chunk = 0; chunk < 2; chunk++) {
      half8 sfr[4];
#pragma unroll
      for (int pt = 0; pt < 4; pt++)
        sfr[pt] = *(const half8*)&A[cur][(pt * 16 + lm) * AST + chunk * 32 +
                                         quad * 8];
#pragma unroll
      for (int j = 0; j < 3; j++)
#pragma unroll
        for (int pt = 0; pt < 4; pt++)
          acc[j][pt] = __builtin_amdgcn_mfma_f32_16x16x32_f16(
              wfr[chunk][j], sfr[pt], acc[j][pt], 0, 0, 0);
    }
    // (4) combine: gathers had the whole MFMA section to land; bilinear
    // weights re-read from gdesc (.zw) to keep peak regs <= 128.
    if (kk < 8) {
#pragma unroll
      for (int i = 0; i < 2; i++) {
        int pl = wv * 16 + i * 8 + pr;
        combine_write(&A[cur ^ 1][pl * AST + ch8 * 8],
                      gdw[((kk + 1) * 64 + pl) * 2 + 1], g00[i], g01[i],
                      g10[i], g11[i]);
      }
    }
    __syncthreads();
  }

  // ---- epilogue: out = (pm + w0) / (1 + |qn0| + |qn1|) ----
  float w0v[4];
#pragma unroll
  for (int r = 0; r < 4; r++) w0v[r] = w0[wv * 16 + quad * 4 + r];
  float* ob = out + (size_t)b * Cc * HWc + pix0;
#pragma unroll
  for (int pt = 0; pt < 4; pt++) {
#pragma unroll
    for (int r = 0; r < 4; r++) {
      int oc = wv * 16 + quad * 4 + r;
      float pm = acc[0][pt][r] + w0v[r];
      float qn = 1.0f + fabsf(acc[1][pt][r]) + fabsf(acc[2][pt][r]);
      ob[oc * HWc + pt * 16 + lm] = pm / qn;
    }
  }
}

extern "C" void kernel_launch(void* const* d_in, const int* in_sizes, int n_in,
                              void* d_out, int out_size, void* d_ws, size_t ws_size,
                              hipStream_t stream) {
  const float* x = (const float*)d_in[0];      // [4,64,160,160]
  const float* off_w = (const float*)d_in[1];  // [18,64]
  const float* off_b = (const float*)d_in[2];  // [18]
  const float* w_m = (const float*)d_in[3];    // [128,64,3,3]
  const float* w_n = (const float*)d_in[4];    // [128,64,3,3]
  const float* w0 = (const float*)d_in[5];     // [64]
  float* out = (float*)d_out;                  // [4,64,160,160]

  // ws layout: bfrag 221184 B | obfrag 4096 B | xT 13107200 B  (~13.3 MB)
  unsigned short* bfrag = (unsigned short*)d_ws;
  unsigned short* obfrag = (unsigned short*)((char*)d_ws + (size_t)221184);
  unsigned short* xT = (unsigned short*)((char*)d_ws + (size_t)225280);

  hipLaunchKernelGGL(k_prep, dim3(840), dim3(256), 0, stream, x, w_m, w_n,
                     off_w, xT, bfrag);
  hipLaunchKernelGGL(k_main, dim3(1600), dim3(256), 0, stream, xT, w0, off_b,
                     bfrag, obfrag, out);
}